// Round 12
// baseline (272.010 us; speedup 1.0000x reference)
//
#include <hip/hip_runtime.h>
#include <hip/hip_fp16.h>

#define N_NODES 50000
#define N_EDGES 800000
#define FDIM 64
#define N_GRAPHS 500
#define OUTF 10
#define SENT N_NODES
#define ROWCAP 64                       // fixed CSR row capacity; Poisson(16), P(deg>64)~1e-18
#define EV4 (N_EDGES / 4)               // 200000 int4 edge quads
#define FB4 ((EV4 + 255) / 256)         // 782 chunks per XCD (256 quads each)
#define SCANB (FB4 * 8)                 // 6256 scan blocks (~1 chunk grab each)
#define CONVB (N_NODES * 16 / 256)      // 3125 x->fp16 convert blocks (exact)
#define SEGB ((N_NODES + 256) / 256)    // 196 seg-start blocks

typedef _Float16 f16x8 __attribute__((ext_vector_type(8)));
typedef float f32x4 __attribute__((ext_vector_type(4)));
typedef float f32x2 __attribute__((ext_vector_type(2)));

struct __align__(8)  H4 { __half2 a, b; };
struct __align__(16) H8 { __half2 a, b, c, d; };

__device__ __forceinline__ float rl(float v, int l) {
    return __int_as_float(__builtin_amdgcn_readlane(__float_as_int(v), l));
}
__device__ __forceinline__ unsigned char f2fp8(float v) {
    return (unsigned char)(__builtin_amdgcn_cvt_pk_fp8_f32(v, v, 0, 0) & 0xff);
}
// L2-local ticket atomic: legal ONLY because all writers of a given word are
// guaranteed on one physical XCD (see fill_seg work assignment). WG scope drops
// the cross-L2 coherence flags -> RMW executes in the local L2 instead of the
// shared fabric atomic point (the R12 hypothesis for fill_seg's ~40us floor).
__device__ __forceinline__ int atomLocal(int* p) {
    return __hip_atomic_fetch_add(p, 1, __ATOMIC_RELAXED, __HIP_MEMORY_SCOPE_WORKGROUP);
}

// ---------------- CSR build (physical-XCD scan) + x->fp16 conv + seg + W swizzle ----------------
// R12: blocks read their PHYSICAL XCD id (s_getreg HW_REG_XCC_ID=20, 0..7 —
// HW-verified m09) and self-assign scan chunks via per-XCD device-scope cursors.
// This upgrades "all writers of a deg/csr line share an XCD" from a dispatch
// heuristic (bid&7) to a hardware guarantee, regardless of block->XCD mapping
// (G16-safe: any mapping completes; skewed mappings just loop more chunks).
// That guarantee makes the per-edge ticket atomics legal at WORKGROUP scope ->
// local-L2 execution, 8 L2s in parallel on disjoint node sets.
__global__ __launch_bounds__(256) void fill_seg(
    const int* __restrict__ src, const int* __restrict__ dst,
    const float* __restrict__ x,
    int* __restrict__ deg, int* __restrict__ csr, int* __restrict__ xcur,
    const int* __restrict__ batch, int* __restrict__ start,
    const float* __restrict__ W1, const float* __restrict__ W2,
    __half* __restrict__ Wh1, __half* __restrict__ Wh2,
    __half* __restrict__ hsr, unsigned char* __restrict__ hs1q) {
    int bid = blockIdx.x, tid = threadIdx.x;
    if (bid < SCANB) {
        __shared__ int sChunk;
        int xcd;
        asm("s_getreg_b32 %0, hwreg(20, 0, 32)" : "=s"(xcd));   // HW_REG_XCC_ID [m09]
        xcd &= 7;
        for (;;) {
            __syncthreads();                     // previous iter's sChunk read done
            if (tid == 0) sChunk = atomicAdd(&xcur[xcd], 1);    // device-scope, 1/block-iter
            __syncthreads();
            int c = sChunk;
            if (c >= FB4) break;                 // this XCD's scan complete
            int t = c * 256 + tid;
            if (t >= EV4) continue;
            int4 d4 = ((const int4*)dst)[t];
            bool m0 = ((d4.x >> 5) & 7) == xcd;
            bool m1 = ((d4.y >> 5) & 7) == xcd;
            bool m2 = ((d4.z >> 5) & 7) == xcd;
            bool m3 = ((d4.w >> 5) & 7) == xcd;
            if (!(m0 | m1 | m2 | m3)) continue;  // early-out before src load
            int4 s4 = ((const int4*)src)[t];
            if (m0) { int p = atomLocal(&deg[d4.x]); if (p < ROWCAP) csr[d4.x * ROWCAP + p] = s4.x; }
            if (m1) { int p = atomLocal(&deg[d4.y]); if (p < ROWCAP) csr[d4.y * ROWCAP + p] = s4.y; }
            if (m2) { int p = atomLocal(&deg[d4.z]); if (p < ROWCAP) csr[d4.z * ROWCAP + p] = s4.z; }
            if (m3) { int p = atomLocal(&deg[d4.w]); if (p < ROWCAP) csr[d4.w * ROWCAP + p] = s4.w; }
        }
    } else if (bid < SCANB + CONVB) {
        if (bid == SCANB && tid < 16) {          // zero hs1q sentinel row (64 B)
            ((unsigned int*)(hs1q + (size_t)N_NODES * FDIM))[tid] = 0u;
        }
        int gid = (bid - SCANB) * 256 + tid;     // float4 index; CONVB*256 == N_NODES*16 exact
        float4 vv = ((const float4*)x)[gid];
        H4 o;
        o.a = __floats2half2_rn(vv.x, vv.y);     // raw (unscaled) fp16 x
        o.b = __floats2half2_rn(vv.z, vv.w);
        ((H4*)hsr)[gid] = o;
    } else if (bid < SCANB + CONVB + SEGB) {
        int i = (bid - SCANB - CONVB) * 256 + tid;
        if (i > N_NODES) return;
        int b  = (i < N_NODES) ? batch[i] : N_GRAPHS;
        int bp = (i == 0) ? -1 : batch[i - 1];
        for (int g = bp + 1; g <= b; ++g) start[g] = i;
    } else {
        int wb = bid - (SCANB + CONVB + SEGB);   // 0: W1, 1: W2
        const float* Ws = wb ? W2 : W1;
        __half*      Wo = wb ? Wh2 : Wh1;
        int o0 = tid * 16;
        #pragma unroll
        for (int i = 0; i < 16; ++i) {
            int o = o0 + i;                      // o = gk*512 + c*8 + j
            int j = o & 7, c = (o >> 3) & 63, gk = o >> 9;
            int k = (gk >> 2) * 32 + (gk & 3) * 8 + j;
            Wo[o] = __float2half_rn(Ws[k * FDIM + c]);
        }
    }
}

// ---------------- dinv + quantize x*dinv -> fp8 e4m3 (64 B/node = ONE cache line) ----------------
// R10-proven: gcn gathers are L2-line-request bound; fp8 rows are 1 line instead
// of 2 -> halves the binding quantity. HW pk encode/decode round-trip consistent.
__global__ __launch_bounds__(256) void prescale(
    const int* __restrict__ deg, const __half* __restrict__ hsr,
    float* __restrict__ dinv, unsigned char* __restrict__ hsq) {
    if (blockIdx.x == 0 && threadIdx.x < 16) {   // zero fp8 sentinel row (64 B)
        ((unsigned int*)(hsq + (size_t)N_NODES * FDIM))[threadIdx.x] = 0u;
    }
    int i = blockIdx.x * 256 + threadIdx.x;      // H8 index: 8 halves per thread
    if (i >= N_NODES * 8) return;
    int n = i >> 3;
    float dn = rsqrtf((float)deg[n] + 1.0f);     // +1 self-loop
    if ((i & 7) == 0) dinv[n] = dn;
    H8 v = ((const H8*)hsr)[i];
    float2 f0 = __half22float2(v.a), f1 = __half22float2(v.b);
    float2 f2 = __half22float2(v.c), f3 = __half22float2(v.d);
    int lo = 0, hi = 0;
    lo = __builtin_amdgcn_cvt_pk_fp8_f32(f0.x * dn, f0.y * dn, lo, 0);
    lo = __builtin_amdgcn_cvt_pk_fp8_f32(f1.x * dn, f1.y * dn, lo, 1);
    hi = __builtin_amdgcn_cvt_pk_fp8_f32(f2.x * dn, f2.y * dn, hi, 0);
    hi = __builtin_amdgcn_cvt_pk_fp8_f32(f3.x * dn, f3.y * dn, hi, 1);
    uint2 q; q.x = (unsigned)lo; q.y = (unsigned)hi;
    ((uint2*)hsq)[i] = q;                        // 8 B per thread, coalesced
}

// ---------------- fused GCN layer: fp8 gather (1 line/row) + MFMA transform ----------------
// R11-proven. BOTH layers gather fp8 (8 B/lane, one 64B line per row). Layer 1
// (!POOL) writes its relu*dinv output as fp8 bytes (wave-local row lines -> L2
// merge); layer 2 (POOL) accumulates graph mean-pool sums via fp32 atomics
// (device scope: pooled is cross-XCD shared).
template <bool POOL>
__global__ __launch_bounds__(256) void gcn_fused(
    const int* __restrict__ deg, const int* __restrict__ csr,
    const float* __restrict__ dinv, const unsigned char* __restrict__ hs,
    const __half* __restrict__ Wh, const float* __restrict__ bias,
    unsigned char* __restrict__ out, const int* __restrict__ batch,
    float* __restrict__ pooled) {
    __shared__ __align__(16) __half A_lds[4][8][72];
    int tid = threadIdx.x;
    int lane = tid & 63;
    int w = tid >> 6;
    int q8 = lane >> 3, L8 = lane & 7;                   // node 0..7, chunk 0..7
    int nodeBase = (blockIdx.x * 4 + w) * 8;             // grid = 1563 (last block partial)
    int myN = nodeBase + q8;
    bool valid = myN < N_NODES;
    int myNc = valid ? myN : SENT;                       // sentinel row = zeros

    float dn = dinv[min(myN, N_NODES - 1)];
    int d = valid ? min(deg[min(myN, N_NODES - 1)], ROWCAP) : 0;
    int row = myNc << 6;
    int dpad = (d + 7) & ~7;

    uint2 sq = *(const uint2*)(hs + (size_t)myNc * FDIM + 8 * L8);   // self term
    f32x2 a0_ = __builtin_amdgcn_cvt_pk_f32_fp8(sq.x, 0);
    f32x2 a1_ = __builtin_amdgcn_cvt_pk_f32_fp8(sq.x, 1);
    f32x2 a2_ = __builtin_amdgcn_cvt_pk_f32_fp8(sq.y, 0);
    f32x2 a3_ = __builtin_amdgcn_cvt_pk_f32_fp8(sq.y, 1);
    float acc[8] = { a0_.x, a0_.y, a1_.x, a1_.y, a2_.x, a2_.y, a3_.x, a3_.y };

    uint2 sA = *(const uint2*)(csr + row);               // index double-buffer
    uint2 sB = *(const uint2*)(csr + row + 2);
    uint2 sC = *(const uint2*)(csr + row + 4);
    uint2 sD = *(const uint2*)(csr + row + 6);
    for (int base = 0; base < dpad; base += 8) {
        int nxt = min(base + 8, 56);                     // stays inside this node's row
        uint2 nA = *(const uint2*)(csr + row + nxt);
        uint2 nB = *(const uint2*)(csr + row + nxt + 2);
        uint2 nC = *(const uint2*)(csr + row + nxt + 4);
        uint2 nD = *(const uint2*)(csr + row + nxt + 6);
        unsigned ss[8] = { sA.x, sA.y, sB.x, sB.y, sC.x, sC.y, sD.x, sD.y };
        #pragma unroll
        for (int j = 0; j < 8; ++j) {
            int e = base + j;
            int s = (e < d) ? (int)ss[j] : SENT;         // mask pad garbage BEFORE load
            uint2 q = *(const uint2*)(hs + (size_t)s * FDIM + 8 * L8);
            f32x2 f0 = __builtin_amdgcn_cvt_pk_f32_fp8(q.x, 0);
            f32x2 f1 = __builtin_amdgcn_cvt_pk_f32_fp8(q.x, 1);
            f32x2 f2 = __builtin_amdgcn_cvt_pk_f32_fp8(q.y, 0);
            f32x2 f3 = __builtin_amdgcn_cvt_pk_f32_fp8(q.y, 1);
            acc[0] += f0.x; acc[1] += f0.y; acc[2] += f1.x; acc[3] += f1.y;
            acc[4] += f2.x; acc[5] += f2.y; acc[6] += f3.x; acc[7] += f3.y;
        }
        sA = nA; sB = nB; sC = nC; sD = nD;
    }
    H8 pk;
    pk.a = __floats2half2_rn(acc[0] * dn, acc[1] * dn);
    pk.b = __floats2half2_rn(acc[2] * dn, acc[3] * dn);
    pk.c = __floats2half2_rn(acc[4] * dn, acc[5] * dn);
    pk.d = __floats2half2_rn(acc[6] * dn, acc[7] * dn);

    // ---- layout swap via wave-private LDS (no block barrier) ----
    *(H8*)&A_lds[w][q8][8 * L8] = pk;
    asm volatile("s_waitcnt lgkmcnt(0)" ::: "memory");
    __builtin_amdgcn_sched_barrier(0);
    int q = (lane >> 4) & 3, L = lane & 15;
    f16x8 a0 = *(const f16x8*)&A_lds[w][lane & 7][q * 8];
    f16x8 a1 = *(const f16x8*)&A_lds[w][lane & 7][32 + q * 8];

    // ---- 8x MFMA: 4 col-tiles, K=64 in two kk steps; C seeded with bias ----
    const f16x8* WB = (const f16x8*)Wh;       // [kk*4+g][c] f16x8, c = ct*16+L
    int cb = q * 64 + L;
    float b0 = bias[L], b1 = bias[16 + L], b2 = bias[32 + L], b3 = bias[48 + L];
    f32x4 C0 = {b0, b0, b0, b0}, C1 = {b1, b1, b1, b1};
    f32x4 C2 = {b2, b2, b2, b2}, C3 = {b3, b3, b3, b3};
    {
        f16x8 B0 = WB[cb], B1 = WB[cb + 16], B2 = WB[cb + 32], B3 = WB[cb + 48];
        C0 = __builtin_amdgcn_mfma_f32_16x16x32_f16(a0, B0, C0, 0, 0, 0);
        C1 = __builtin_amdgcn_mfma_f32_16x16x32_f16(a0, B1, C1, 0, 0, 0);
        C2 = __builtin_amdgcn_mfma_f32_16x16x32_f16(a0, B2, C2, 0, 0, 0);
        C3 = __builtin_amdgcn_mfma_f32_16x16x32_f16(a0, B3, C3, 0, 0, 0);
    }
    {
        f16x8 B0 = WB[cb + 256], B1 = WB[cb + 272], B2 = WB[cb + 288], B3 = WB[cb + 304];
        C0 = __builtin_amdgcn_mfma_f32_16x16x32_f16(a1, B0, C0, 0, 0, 0);
        C1 = __builtin_amdgcn_mfma_f32_16x16x32_f16(a1, B1, C1, 0, 0, 0);
        C2 = __builtin_amdgcn_mfma_f32_16x16x32_f16(a1, B2, C2, 0, 0, 0);
        C3 = __builtin_amdgcn_mfma_f32_16x16x32_f16(a1, B3, C3, 0, 0, 0);
    }

    // ---- epilogue: lane<32 holds rows 0-7 (node = nodeBase + (lane>>4)*4 + reg) ----
    int col = lane & 15;
    int half = (lane >> 4) & 1;
    if (POOL) {
        float p0 = fmaxf(C0[0],0.f)+fmaxf(C0[1],0.f)+fmaxf(C0[2],0.f)+fmaxf(C0[3],0.f);
        float p1 = fmaxf(C1[0],0.f)+fmaxf(C1[1],0.f)+fmaxf(C1[2],0.f)+fmaxf(C1[3],0.f);
        float p2 = fmaxf(C2[0],0.f)+fmaxf(C2[1],0.f)+fmaxf(C2[2],0.f)+fmaxf(C2[3],0.f);
        float p3 = fmaxf(C3[0],0.f)+fmaxf(C3[1],0.f)+fmaxf(C3[2],0.f)+fmaxf(C3[3],0.f);
        p0 += __shfl_down(p0, 16); p1 += __shfl_down(p1, 16);
        p2 += __shfl_down(p2, 16); p3 += __shfl_down(p3, 16);
        bool allv = (nodeBase + 7) < N_NODES;
        int g0 = batch[min(nodeBase,     N_NODES - 1)];
        int gL = batch[min(nodeBase + 7, N_NODES - 1)];
        if (allv && g0 == gL) {
            if (lane < 16) {
                atomicAdd(&pooled[g0 * FDIM +      col], p0);
                atomicAdd(&pooled[g0 * FDIM + 16 + col], p1);
                atomicAdd(&pooled[g0 * FDIM + 32 + col], p2);
                atomicAdd(&pooled[g0 * FDIM + 48 + col], p3);
            }
        } else if (lane < 32) {
            #pragma unroll
            for (int r = 0; r < 4; ++r) {
                int node = nodeBase + half * 4 + r;
                if (node < N_NODES) {
                    int g = batch[node];
                    atomicAdd(&pooled[g * FDIM +      col], fmaxf(C0[r], 0.f));
                    atomicAdd(&pooled[g * FDIM + 16 + col], fmaxf(C1[r], 0.f));
                    atomicAdd(&pooled[g * FDIM + 32 + col], fmaxf(C2[r], 0.f));
                    atomicAdd(&pooled[g * FDIM + 48 + col], fmaxf(C3[r], 0.f));
                }
            }
        }
    } else if (lane < 32) {
        // write relu(h1)*dinv as fp8 bytes: row lines are wave-local -> L2 merges
        #pragma unroll
        for (int r = 0; r < 4; ++r) {
            int nl = half * 4 + r;
            int node = nodeBase + nl;
            if (node < N_NODES) {
                float sc = __shfl(dn, nl * 8);            // dn lives on lanes q8*8
                size_t ro = (size_t)node * FDIM;
                out[ro +      col] = f2fp8(fmaxf(C0[r], 0.f) * sc);
                out[ro + 16 + col] = f2fp8(fmaxf(C1[r], 0.f) * sc);
                out[ro + 32 + col] = f2fp8(fmaxf(C2[r], 0.f) * sc);
                out[ro + 48 + col] = f2fp8(fmaxf(C3[r], 0.f) * sc);
            }
        }
    }
}

// ---------------- tiny head: mean + linear + log_softmax from pooled sums ----------------
__global__ __launch_bounds__(256) void head(
    const float* __restrict__ pooled, const int* __restrict__ start,
    const float* __restrict__ Wc, const float* __restrict__ bc,
    float* __restrict__ out) {
    int tid = threadIdx.x;
    int lane = tid & 63;
    int g = blockIdx.x * 4 + (tid >> 6);
    int cnt = start[g + 1] - start[g];
    float c = (float)(cnt > 1 ? cnt : 1);
    float pm = pooled[g * FDIM + lane] / c;

    int j = (lane < OUTF) ? lane : 0;
    float a = bc[j];
    #pragma unroll
    for (int k = 0; k < 64; ++k) a = fmaf(rl(pm, k), Wc[k * OUTF + j], a);

    float m = -1e30f;
    #pragma unroll
    for (int i = 0; i < OUTF; ++i) m = fmaxf(m, rl(a, i));
    float s = 0.f;
    #pragma unroll
    for (int i = 0; i < OUTF; ++i) s += __expf(rl(a, i) - m);
    float lse = m + __logf(s);
    if (lane < OUTF) out[g * OUTF + lane] = a - lse;
}

extern "C" void kernel_launch(void* const* d_in, const int* in_sizes, int n_in,
                              void* d_out, int out_size, void* d_ws, size_t ws_size,
                              hipStream_t stream) {
    const float* x     = (const float*)d_in[0];
    const int*   ei    = (const int*)d_in[1];
    const int*   batch = (const int*)d_in[2];
    const float* W1    = (const float*)d_in[3];
    const float* b1    = (const float*)d_in[4];
    const float* W2    = (const float*)d_in[5];
    const float* b2    = (const float*)d_in[6];
    const float* Wc    = (const float*)d_in[7];
    const float* bc    = (const float*)d_in[8];
    float* out = (float*)d_out;

    const int* src = ei;
    const int* dst = ei + N_EDGES;

    // workspace layout (bytes): fp8 tables FIRST so every 64B node row is
    // line-aligned. xcur (per-XCD chunk cursors) inside the memset region.
    unsigned char* wsb  = (unsigned char*)d_ws;
    unsigned char* hsq  = wsb;                                  // (N+1)*64 B, 64B-aligned
    unsigned char* hs1q = hsq + (size_t)(N_NODES + 1) * FDIM;   // (N+1)*64 B, 64B-aligned
    int*    deg    = (int*)(hs1q + (size_t)(N_NODES + 1) * FDIM);  // 50000 (memset to 0)
    float*  pooled = (float*)(deg + N_NODES);                   // 500*64 (memset to 0)
    int*    xcur   = (int*)(pooled + N_GRAPHS * FDIM);          // 16 (memset to 0)
    float*  dinv   = (float*)(xcur + 16);                       // 50000
    int*    start  = (int*)(dinv + N_NODES);                    // 504
    int*    csr    = start + N_GRAPHS + 4;                      // 3.2M ints, 16B-aligned
    __half* hsr    = (__half*)(csr + N_NODES * ROWCAP);         // N*64 halves (raw fp16 x)
    __half* Wh1    = hsr + (size_t)N_NODES * FDIM;              // 4096 halves
    __half* Wh2    = Wh1 + FDIM * FDIM;                         // 4096 halves

    hipMemsetAsync(deg, 0, (N_NODES + N_GRAPHS * FDIM + 16) * sizeof(int), stream);

    fill_seg <<<SCANB + CONVB + SEGB + 2, 256, 0, stream>>>(
        src, dst, x, deg, csr, xcur, batch, start, W1, W2, Wh1, Wh2, hsr, hs1q);
    prescale <<<(N_NODES * 8 + 255) / 256, 256, 0, stream>>>(deg, hsr, dinv, hsq);

    const int gcnGrid = (N_NODES + 31) / 32;  // 1563, 8 nodes/wave
    gcn_fused<false><<<gcnGrid, 256, 0, stream>>>(deg, csr, dinv, hsq,  Wh1, b1, hs1q, nullptr, nullptr);
    gcn_fused<true ><<<gcnGrid, 256, 0, stream>>>(deg, csr, dinv, hs1q, Wh2, b2, nullptr, batch, pooled);

    head<<<N_GRAPHS / 4, 256, 0, stream>>>(pooled, start, Wc, bc, out);
}

// Round 13
// 154.883 us; speedup vs baseline: 1.7562x; 1.7562x over previous
//
#include <hip/hip_runtime.h>
#include <hip/hip_fp16.h>

#define N_NODES 50000
#define N_EDGES 800000
#define FDIM 64
#define N_GRAPHS 500
#define OUTF 10
#define SENT N_NODES
#define ROWCAP 64                       // fixed CSR row capacity; Poisson(16), P(deg>64)~1e-18
#define EV4 (N_EDGES / 4)               // 200000 int4 edge quads
#define FB4 ((EV4 + 255) / 256)         // 782 blocks per XCD group
#define SCANB (FB4 * 8)                 // 6256 scan blocks (8 affinity groups)
#define CONVB (N_NODES * 16 / 256)      // 3125 x->fp16 convert blocks (exact)
#define SEGB ((N_NODES + 256) / 256)    // 196 seg-start blocks

typedef _Float16 f16x8 __attribute__((ext_vector_type(8)));
typedef float f32x4 __attribute__((ext_vector_type(4)));
typedef float f32x2 __attribute__((ext_vector_type(2)));

struct __align__(8)  H4 { __half2 a, b; };
struct __align__(16) H8 { __half2 a, b, c, d; };

__device__ __forceinline__ float rl(float v, int l) {
    return __int_as_float(__builtin_amdgcn_readlane(__float_as_int(v), l));
}
__device__ __forceinline__ unsigned char f2fp8(float v) {
    return (unsigned char)(__builtin_amdgcn_cvt_pk_fp8_f32(v, v, 0, 0) & 0xff);
}

// ---------------- CSR build (XCD-affinity scan) + x->fp16 conv + seg + W swizzle ----------------
// R11-proven (best: 156.35us). Scan is atomic-bound -> the x->fp16 conversion
// rides under it free. Affinity ((d>>5)&7 == bid&7) keeps csr/deg lines
// single-XCD-owned. R12 lesson: static chunk assignment beats dynamic grabbing
// (per-chunk cursor atomic + barriers serialized each block's pipeline, 43->158us);
// five CSR-build structures bracket the ticket-atomic floor at ~43us.
__global__ __launch_bounds__(256) void fill_seg(
    const int* __restrict__ src, const int* __restrict__ dst,
    const float* __restrict__ x,
    int* __restrict__ deg, int* __restrict__ csr,
    const int* __restrict__ batch, int* __restrict__ start,
    const float* __restrict__ W1, const float* __restrict__ W2,
    __half* __restrict__ Wh1, __half* __restrict__ Wh2,
    __half* __restrict__ hsr, unsigned char* __restrict__ hs1q) {
    int bid = blockIdx.x, tid = threadIdx.x;
    if (bid < SCANB) {
        int myx = bid & 7;                       // XCD proxy (dispatch round-robin)
        int t = (bid >> 3) * 256 + tid;
        if (t >= EV4) return;
        int4 d4 = ((const int4*)dst)[t];
        bool m0 = ((d4.x >> 5) & 7) == myx;
        bool m1 = ((d4.y >> 5) & 7) == myx;
        bool m2 = ((d4.z >> 5) & 7) == myx;
        bool m3 = ((d4.w >> 5) & 7) == myx;
        if (!(m0 | m1 | m2 | m3)) return;        // early-out before src load
        int4 s4 = ((const int4*)src)[t];
        if (m0) { int p = atomicAdd(&deg[d4.x], 1); if (p < ROWCAP) csr[d4.x * ROWCAP + p] = s4.x; }
        if (m1) { int p = atomicAdd(&deg[d4.y], 1); if (p < ROWCAP) csr[d4.y * ROWCAP + p] = s4.y; }
        if (m2) { int p = atomicAdd(&deg[d4.z], 1); if (p < ROWCAP) csr[d4.z * ROWCAP + p] = s4.z; }
        if (m3) { int p = atomicAdd(&deg[d4.w], 1); if (p < ROWCAP) csr[d4.w * ROWCAP + p] = s4.w; }
    } else if (bid < SCANB + CONVB) {
        if (bid == SCANB && tid < 16) {          // zero hs1q sentinel row (64 B)
            ((unsigned int*)(hs1q + (size_t)N_NODES * FDIM))[tid] = 0u;
        }
        int gid = (bid - SCANB) * 256 + tid;     // float4 index; CONVB*256 == N_NODES*16 exact
        float4 vv = ((const float4*)x)[gid];
        H4 o;
        o.a = __floats2half2_rn(vv.x, vv.y);     // raw (unscaled) fp16 x
        o.b = __floats2half2_rn(vv.z, vv.w);
        ((H4*)hsr)[gid] = o;
    } else if (bid < SCANB + CONVB + SEGB) {
        int i = (bid - SCANB - CONVB) * 256 + tid;
        if (i > N_NODES) return;
        int b  = (i < N_NODES) ? batch[i] : N_GRAPHS;
        int bp = (i == 0) ? -1 : batch[i - 1];
        for (int g = bp + 1; g <= b; ++g) start[g] = i;
    } else {
        int wb = bid - (SCANB + CONVB + SEGB);   // 0: W1, 1: W2
        const float* Ws = wb ? W2 : W1;
        __half*      Wo = wb ? Wh2 : Wh1;
        int o0 = tid * 16;
        #pragma unroll
        for (int i = 0; i < 16; ++i) {
            int o = o0 + i;                      // o = gk*512 + c*8 + j
            int j = o & 7, c = (o >> 3) & 63, gk = o >> 9;
            int k = (gk >> 2) * 32 + (gk & 3) * 8 + j;
            Wo[o] = __float2half_rn(Ws[k * FDIM + c]);
        }
    }
}

// ---------------- dinv + quantize x*dinv -> fp8 e4m3 (64 B/node = ONE cache line) ----------------
// R10-proven: gcn gathers are L2-line-request bound; fp8 rows are 1 line instead
// of 2 -> halves the binding quantity. HW pk encode/decode round-trip consistent.
__global__ __launch_bounds__(256) void prescale(
    const int* __restrict__ deg, const __half* __restrict__ hsr,
    float* __restrict__ dinv, unsigned char* __restrict__ hsq) {
    if (blockIdx.x == 0 && threadIdx.x < 16) {   // zero fp8 sentinel row (64 B)
        ((unsigned int*)(hsq + (size_t)N_NODES * FDIM))[threadIdx.x] = 0u;
    }
    int i = blockIdx.x * 256 + threadIdx.x;      // H8 index: 8 halves per thread
    if (i >= N_NODES * 8) return;
    int n = i >> 3;
    float dn = rsqrtf((float)deg[n] + 1.0f);     // +1 self-loop
    if ((i & 7) == 0) dinv[n] = dn;
    H8 v = ((const H8*)hsr)[i];
    float2 f0 = __half22float2(v.a), f1 = __half22float2(v.b);
    float2 f2 = __half22float2(v.c), f3 = __half22float2(v.d);
    int lo = 0, hi = 0;
    lo = __builtin_amdgcn_cvt_pk_fp8_f32(f0.x * dn, f0.y * dn, lo, 0);
    lo = __builtin_amdgcn_cvt_pk_fp8_f32(f1.x * dn, f1.y * dn, lo, 1);
    hi = __builtin_amdgcn_cvt_pk_fp8_f32(f2.x * dn, f2.y * dn, hi, 0);
    hi = __builtin_amdgcn_cvt_pk_fp8_f32(f3.x * dn, f3.y * dn, hi, 1);
    uint2 q; q.x = (unsigned)lo; q.y = (unsigned)hi;
    ((uint2*)hsq)[i] = q;                        // 8 B per thread, coalesced
}

// ---------------- fused GCN layer: fp8 gather (1 line/row) + MFMA transform ----------------
// R11-proven. BOTH layers gather fp8 (8 B/lane, one 64B line per row). Layer 1
// (!POOL) writes its relu*dinv output as fp8 bytes (wave-local row lines -> L2
// merge); layer 2 (POOL) accumulates graph mean-pool sums via fp32 atomics.
// A-tile rows 0-7 = 8 real nodes (rows 8-15 dup; C rows 8-15 ignored). LDS
// stride 72 conflict-free. Epilogue lanes 0-31 (C: col=lane&15, row=(lane>>4)*4+reg).
template <bool POOL>
__global__ __launch_bounds__(256) void gcn_fused(
    const int* __restrict__ deg, const int* __restrict__ csr,
    const float* __restrict__ dinv, const unsigned char* __restrict__ hs,
    const __half* __restrict__ Wh, const float* __restrict__ bias,
    unsigned char* __restrict__ out, const int* __restrict__ batch,
    float* __restrict__ pooled) {
    __shared__ __align__(16) __half A_lds[4][8][72];
    int tid = threadIdx.x;
    int lane = tid & 63;
    int w = tid >> 6;
    int q8 = lane >> 3, L8 = lane & 7;                   // node 0..7, chunk 0..7
    int nodeBase = (blockIdx.x * 4 + w) * 8;             // grid = 1563 (last block partial)
    int myN = nodeBase + q8;
    bool valid = myN < N_NODES;
    int myNc = valid ? myN : SENT;                       // sentinel row = zeros

    float dn = dinv[min(myN, N_NODES - 1)];
    int d = valid ? min(deg[min(myN, N_NODES - 1)], ROWCAP) : 0;
    int row = myNc << 6;
    int dpad = (d + 7) & ~7;

    uint2 sq = *(const uint2*)(hs + (size_t)myNc * FDIM + 8 * L8);   // self term
    f32x2 a0_ = __builtin_amdgcn_cvt_pk_f32_fp8(sq.x, 0);
    f32x2 a1_ = __builtin_amdgcn_cvt_pk_f32_fp8(sq.x, 1);
    f32x2 a2_ = __builtin_amdgcn_cvt_pk_f32_fp8(sq.y, 0);
    f32x2 a3_ = __builtin_amdgcn_cvt_pk_f32_fp8(sq.y, 1);
    float acc[8] = { a0_.x, a0_.y, a1_.x, a1_.y, a2_.x, a2_.y, a3_.x, a3_.y };

    uint2 sA = *(const uint2*)(csr + row);               // index double-buffer
    uint2 sB = *(const uint2*)(csr + row + 2);
    uint2 sC = *(const uint2*)(csr + row + 4);
    uint2 sD = *(const uint2*)(csr + row + 6);
    for (int base = 0; base < dpad; base += 8) {
        int nxt = min(base + 8, 56);                     // stays inside this node's row
        uint2 nA = *(const uint2*)(csr + row + nxt);
        uint2 nB = *(const uint2*)(csr + row + nxt + 2);
        uint2 nC = *(const uint2*)(csr + row + nxt + 4);
        uint2 nD = *(const uint2*)(csr + row + nxt + 6);
        unsigned ss[8] = { sA.x, sA.y, sB.x, sB.y, sC.x, sC.y, sD.x, sD.y };
        #pragma unroll
        for (int j = 0; j < 8; ++j) {
            int e = base + j;
            int s = (e < d) ? (int)ss[j] : SENT;         // mask pad garbage BEFORE load
            uint2 q = *(const uint2*)(hs + (size_t)s * FDIM + 8 * L8);
            f32x2 f0 = __builtin_amdgcn_cvt_pk_f32_fp8(q.x, 0);
            f32x2 f1 = __builtin_amdgcn_cvt_pk_f32_fp8(q.x, 1);
            f32x2 f2 = __builtin_amdgcn_cvt_pk_f32_fp8(q.y, 0);
            f32x2 f3 = __builtin_amdgcn_cvt_pk_f32_fp8(q.y, 1);
            acc[0] += f0.x; acc[1] += f0.y; acc[2] += f1.x; acc[3] += f1.y;
            acc[4] += f2.x; acc[5] += f2.y; acc[6] += f3.x; acc[7] += f3.y;
        }
        sA = nA; sB = nB; sC = nC; sD = nD;
    }
    H8 pk;
    pk.a = __floats2half2_rn(acc[0] * dn, acc[1] * dn);
    pk.b = __floats2half2_rn(acc[2] * dn, acc[3] * dn);
    pk.c = __floats2half2_rn(acc[4] * dn, acc[5] * dn);
    pk.d = __floats2half2_rn(acc[6] * dn, acc[7] * dn);

    // ---- layout swap via wave-private LDS (no block barrier) ----
    *(H8*)&A_lds[w][q8][8 * L8] = pk;
    asm volatile("s_waitcnt lgkmcnt(0)" ::: "memory");
    __builtin_amdgcn_sched_barrier(0);
    int q = (lane >> 4) & 3, L = lane & 15;
    f16x8 a0 = *(const f16x8*)&A_lds[w][lane & 7][q * 8];
    f16x8 a1 = *(const f16x8*)&A_lds[w][lane & 7][32 + q * 8];

    // ---- 8x MFMA: 4 col-tiles, K=64 in two kk steps; C seeded with bias ----
    const f16x8* WB = (const f16x8*)Wh;       // [kk*4+g][c] f16x8, c = ct*16+L
    int cb = q * 64 + L;
    float b0 = bias[L], b1 = bias[16 + L], b2 = bias[32 + L], b3 = bias[48 + L];
    f32x4 C0 = {b0, b0, b0, b0}, C1 = {b1, b1, b1, b1};
    f32x4 C2 = {b2, b2, b2, b2}, C3 = {b3, b3, b3, b3};
    {
        f16x8 B0 = WB[cb], B1 = WB[cb + 16], B2 = WB[cb + 32], B3 = WB[cb + 48];
        C0 = __builtin_amdgcn_mfma_f32_16x16x32_f16(a0, B0, C0, 0, 0, 0);
        C1 = __builtin_amdgcn_mfma_f32_16x16x32_f16(a0, B1, C1, 0, 0, 0);
        C2 = __builtin_amdgcn_mfma_f32_16x16x32_f16(a0, B2, C2, 0, 0, 0);
        C3 = __builtin_amdgcn_mfma_f32_16x16x32_f16(a0, B3, C3, 0, 0, 0);
    }
    {
        f16x8 B0 = WB[cb + 256], B1 = WB[cb + 272], B2 = WB[cb + 288], B3 = WB[cb + 304];
        C0 = __builtin_amdgcn_mfma_f32_16x16x32_f16(a1, B0, C0, 0, 0, 0);
        C1 = __builtin_amdgcn_mfma_f32_16x16x32_f16(a1, B1, C1, 0, 0, 0);
        C2 = __builtin_amdgcn_mfma_f32_16x16x32_f16(a1, B2, C2, 0, 0, 0);
        C3 = __builtin_amdgcn_mfma_f32_16x16x32_f16(a1, B3, C3, 0, 0, 0);
    }

    // ---- epilogue: lane<32 holds rows 0-7 (node = nodeBase + (lane>>4)*4 + reg) ----
    int col = lane & 15;
    int half = (lane >> 4) & 1;
    if (POOL) {
        float p0 = fmaxf(C0[0],0.f)+fmaxf(C0[1],0.f)+fmaxf(C0[2],0.f)+fmaxf(C0[3],0.f);
        float p1 = fmaxf(C1[0],0.f)+fmaxf(C1[1],0.f)+fmaxf(C1[2],0.f)+fmaxf(C1[3],0.f);
        float p2 = fmaxf(C2[0],0.f)+fmaxf(C2[1],0.f)+fmaxf(C2[2],0.f)+fmaxf(C2[3],0.f);
        float p3 = fmaxf(C3[0],0.f)+fmaxf(C3[1],0.f)+fmaxf(C3[2],0.f)+fmaxf(C3[3],0.f);
        p0 += __shfl_down(p0, 16); p1 += __shfl_down(p1, 16);
        p2 += __shfl_down(p2, 16); p3 += __shfl_down(p3, 16);
        bool allv = (nodeBase + 7) < N_NODES;
        int g0 = batch[min(nodeBase,     N_NODES - 1)];
        int gL = batch[min(nodeBase + 7, N_NODES - 1)];
        if (allv && g0 == gL) {
            if (lane < 16) {
                atomicAdd(&pooled[g0 * FDIM +      col], p0);
                atomicAdd(&pooled[g0 * FDIM + 16 + col], p1);
                atomicAdd(&pooled[g0 * FDIM + 32 + col], p2);
                atomicAdd(&pooled[g0 * FDIM + 48 + col], p3);
            }
        } else if (lane < 32) {
            #pragma unroll
            for (int r = 0; r < 4; ++r) {
                int node = nodeBase + half * 4 + r;
                if (node < N_NODES) {
                    int g = batch[node];
                    atomicAdd(&pooled[g * FDIM +      col], fmaxf(C0[r], 0.f));
                    atomicAdd(&pooled[g * FDIM + 16 + col], fmaxf(C1[r], 0.f));
                    atomicAdd(&pooled[g * FDIM + 32 + col], fmaxf(C2[r], 0.f));
                    atomicAdd(&pooled[g * FDIM + 48 + col], fmaxf(C3[r], 0.f));
                }
            }
        }
    } else if (lane < 32) {
        // write relu(h1)*dinv as fp8 bytes: row lines are wave-local -> L2 merges
        #pragma unroll
        for (int r = 0; r < 4; ++r) {
            int nl = half * 4 + r;
            int node = nodeBase + nl;
            if (node < N_NODES) {
                float sc = __shfl(dn, nl * 8);            // dn lives on lanes q8*8
                size_t ro = (size_t)node * FDIM;
                out[ro +      col] = f2fp8(fmaxf(C0[r], 0.f) * sc);
                out[ro + 16 + col] = f2fp8(fmaxf(C1[r], 0.f) * sc);
                out[ro + 32 + col] = f2fp8(fmaxf(C2[r], 0.f) * sc);
                out[ro + 48 + col] = f2fp8(fmaxf(C3[r], 0.f) * sc);
            }
        }
    }
}

// ---------------- tiny head: mean + linear + log_softmax from pooled sums ----------------
__global__ __launch_bounds__(256) void head(
    const float* __restrict__ pooled, const int* __restrict__ start,
    const float* __restrict__ Wc, const float* __restrict__ bc,
    float* __restrict__ out) {
    int tid = threadIdx.x;
    int lane = tid & 63;
    int g = blockIdx.x * 4 + (tid >> 6);
    int cnt = start[g + 1] - start[g];
    float c = (float)(cnt > 1 ? cnt : 1);
    float pm = pooled[g * FDIM + lane] / c;

    int j = (lane < OUTF) ? lane : 0;
    float a = bc[j];
    #pragma unroll
    for (int k = 0; k < 64; ++k) a = fmaf(rl(pm, k), Wc[k * OUTF + j], a);

    float m = -1e30f;
    #pragma unroll
    for (int i = 0; i < OUTF; ++i) m = fmaxf(m, rl(a, i));
    float s = 0.f;
    #pragma unroll
    for (int i = 0; i < OUTF; ++i) s += __expf(rl(a, i) - m);
    float lse = m + __logf(s);
    if (lane < OUTF) out[g * OUTF + lane] = a - lse;
}

extern "C" void kernel_launch(void* const* d_in, const int* in_sizes, int n_in,
                              void* d_out, int out_size, void* d_ws, size_t ws_size,
                              hipStream_t stream) {
    const float* x     = (const float*)d_in[0];
    const int*   ei    = (const int*)d_in[1];
    const int*   batch = (const int*)d_in[2];
    const float* W1    = (const float*)d_in[3];
    const float* b1    = (const float*)d_in[4];
    const float* W2    = (const float*)d_in[5];
    const float* b2    = (const float*)d_in[6];
    const float* Wc    = (const float*)d_in[7];
    const float* bc    = (const float*)d_in[8];
    float* out = (float*)d_out;

    const int* src = ei;
    const int* dst = ei + N_EDGES;

    // workspace layout (bytes): fp8 tables FIRST so every 64B node row is
    // line-aligned (the "1 row = 1 line" claim depends on it).
    unsigned char* wsb  = (unsigned char*)d_ws;
    unsigned char* hsq  = wsb;                                  // (N+1)*64 B, 64B-aligned
    unsigned char* hs1q = hsq + (size_t)(N_NODES + 1) * FDIM;   // (N+1)*64 B, 64B-aligned
    int*    deg    = (int*)(hs1q + (size_t)(N_NODES + 1) * FDIM);  // 50000 (memset to 0)
    float*  pooled = (float*)(deg + N_NODES);                   // 500*64 (memset to 0)
    float*  dinv   = pooled + N_GRAPHS * FDIM;                  // 50000
    int*    start  = (int*)(dinv + N_NODES);                    // 504
    int*    csr    = start + N_GRAPHS + 4;                      // 3.2M ints, 16B-aligned
    __half* hsr    = (__half*)(csr + N_NODES * ROWCAP);         // N*64 halves (raw fp16 x)
    __half* Wh1    = hsr + (size_t)N_NODES * FDIM;              // 4096 halves
    __half* Wh2    = Wh1 + FDIM * FDIM;                         // 4096 halves

    hipMemsetAsync(deg, 0, (N_NODES + N_GRAPHS * FDIM) * sizeof(int), stream);

    fill_seg <<<SCANB + CONVB + SEGB + 2, 256, 0, stream>>>(
        src, dst, x, deg, csr, batch, start, W1, W2, Wh1, Wh2, hsr, hs1q);
    prescale <<<(N_NODES * 8 + 255) / 256, 256, 0, stream>>>(deg, hsr, dinv, hsq);

    const int gcnGrid = (N_NODES + 31) / 32;  // 1563, 8 nodes/wave
    gcn_fused<false><<<gcnGrid, 256, 0, stream>>>(deg, csr, dinv, hsq,  Wh1, b1, hs1q, nullptr, nullptr);
    gcn_fused<true ><<<gcnGrid, 256, 0, stream>>>(deg, csr, dinv, hs1q, Wh2, b2, nullptr, batch, pooled);

    head<<<N_GRAPHS / 4, 256, 0, stream>>>(pooled, start, Wc, bc, out);
}